// Round 1
// baseline (15182.326 us; speedup 1.0000x reference)
//
#include <hip/hip_runtime.h>
#include <hip/hip_bf16.h>

// Problem constants (match reference)
constexpr int Bc   = 2;
constexpr int Tc   = 1024;
constexpr int Vc   = 50257;
constexpr int Lc   = 8;
constexpr int Dc   = 1024;
constexpr int Hc   = 16;
constexpr int HKVc = 4;
constexpr int HDc  = 64;     // D/H
constexpr int KVDc = 256;    // HKV*HD
constexpr int MLPc = 4096;   // 4*D
constexpr int BVc  = 65536;
constexpr int BDc  = 256;
constexpr int VEDc = 128;

constexpr int NTOK = Bc * Tc;          // 2048
constexpr long SZ_X  = (long)NTOK * Dc;    // 2,097,152
constexpr long SZ_KV = (long)NTOK * KVDc;  // 524,288
constexpr long SZ_H  = (long)NTOK * MLPc;  // 8,388,608

#define NEG_BIG (-3.0e38f)

__device__ __forceinline__ float wave_sum(float v) {
#pragma unroll
  for (int off = 32; off >= 1; off >>= 1) v += __shfl_xor(v, off);
  return v;
}
__device__ __forceinline__ float wave_max(float v) {
#pragma unroll
  for (int off = 32; off >= 1; off >>= 1) v = fmaxf(v, __shfl_xor(v, off));
  return v;
}

// ---------------------------------------------------------------------------
// Embedding: raw_x = rms(embed_w[id]) + big_w[bg] @ big_proj.T * big_scale
//            vemb  = ve_w[id] @ ve_proj.T * ve_scale
// One block (256 threads) per token.
// ---------------------------------------------------------------------------
__global__ __launch_bounds__(256) void embed_kernel(
    const int* __restrict__ ids, const float* __restrict__ embed_w,
    const float* __restrict__ big_w, const float* __restrict__ big_proj,
    const float* __restrict__ big_scale, const float* __restrict__ ve_w,
    const float* __restrict__ ve_proj, const float* __restrict__ ve_scale,
    float* __restrict__ raw_x, float* __restrict__ vemb) {
  int bt = blockIdx.x;
  int tid = threadIdx.x;
  int t = bt % Tc;
  int tok = ids[bt];

  const float* e = embed_w + (size_t)tok * Dc;
  float ev[4];
  float ss = 0.f;
#pragma unroll
  for (int i = 0; i < 4; ++i) {
    ev[i] = e[tid + i * 256];
    ss += ev[i] * ev[i];
  }
  __shared__ float red[4];
  __shared__ float brow[BDc];
  __shared__ float verow[VEDc];
  float wsum = wave_sum(ss);
  if ((tid & 63) == 0) red[tid >> 6] = wsum;

  // bigram hash index
  int bg;
  if (t == 0) {
    bg = BVc - 1;
  } else {
    unsigned a = (unsigned)ids[bt];
    unsigned p = (unsigned)ids[bt - 1];
    bg = (int)(((36313u * a) ^ (27191u * p)) % 65535u);
  }
  brow[tid] = big_w[(size_t)bg * BDc + tid];
  if (tid < VEDc) verow[tid] = ve_w[(size_t)tok * VEDc + tid];
  __syncthreads();

  float tot = red[0] + red[1] + red[2] + red[3];
  float rn = rsqrtf(tot / (float)Dc + 1e-6f);
  float bs = big_scale[0];
#pragma unroll
  for (int i = 0; i < 4; ++i) {
    int d = tid + i * 256;
    const float* bp = big_proj + (size_t)d * BDc;
    float dot = 0.f;
    for (int c = 0; c < BDc; ++c) dot += brow[c] * bp[c];
    raw_x[(size_t)bt * Dc + d] = ev[i] * rn + dot * bs;
  }
  {
    float vs = ve_scale[0];
    int d = tid;  // 0..255
    const float* vp = ve_proj + (size_t)d * VEDc;
    float dot = 0.f;
    for (int c = 0; c < VEDc; ++c) dot += verow[c] * vp[c];
    vemb[(size_t)bt * KVDc + d] = dot * vs;
  }
}

// ---------------------------------------------------------------------------
// Smear: x = (1-g)*raw + g*raw_prev_token ; x0 = x
// ---------------------------------------------------------------------------
__global__ __launch_bounds__(256) void smear_kernel(
    const float* __restrict__ raw, const float* __restrict__ gate,
    float* __restrict__ x, float* __restrict__ x0) {
  long idx = (long)blockIdx.x * 256 + threadIdx.x;
  if (idx >= SZ_X) return;
  int d = (int)(idx & (Dc - 1));
  int t = (int)((idx / Dc) & (Tc - 1));
  float g = 1.f / (1.f + expf(-gate[d]));
  float cur = raw[idx];
  float prev = (t > 0) ? raw[idx - Dc] : 0.f;
  float val = (1.f - g) * cur + g * prev;
  x[idx] = val;
  x0[idx] = val;
}

// ---------------------------------------------------------------------------
// Pre-layer: x_in = mix0*x + mix1*x0 ; xn = rms(x_in). Block per token.
// ---------------------------------------------------------------------------
__global__ __launch_bounds__(256) void prelayer_kernel(
    const float* __restrict__ x, const float* __restrict__ x0,
    const float* __restrict__ mix, float* __restrict__ x_in,
    float* __restrict__ xn) {
  int bt = blockIdx.x;
  int tid = threadIdx.x;
  const float* xr = x + (size_t)bt * Dc;
  const float* x0r = x0 + (size_t)bt * Dc;
  float vals[4];
  float ss = 0.f;
#pragma unroll
  for (int i = 0; i < 4; ++i) {
    int d = tid + i * 256;
    float v = mix[d] * xr[d] + mix[Dc + d] * x0r[d];
    vals[i] = v;
    ss += v * v;
  }
  __shared__ float red[4];
  float wsum = wave_sum(ss);
  if ((tid & 63) == 0) red[tid >> 6] = wsum;
  __syncthreads();
  float tot = red[0] + red[1] + red[2] + red[3];
  float rn = rsqrtf(tot / (float)Dc + 1e-6f);
#pragma unroll
  for (int i = 0; i < 4; ++i) {
    int d = tid + i * 256;
    x_in[(size_t)bt * Dc + d] = vals[i];
    xn[(size_t)bt * Dc + d] = vals[i] * rn;
  }
}

// ---------------------------------------------------------------------------
// Plain RMS over D. Block per token.
// ---------------------------------------------------------------------------
__global__ __launch_bounds__(256) void rms_kernel(const float* __restrict__ in,
                                                  float* __restrict__ out) {
  int bt = blockIdx.x;
  int tid = threadIdx.x;
  const float* p = in + (size_t)bt * Dc;
  float v[4];
  float ss = 0.f;
#pragma unroll
  for (int i = 0; i < 4; ++i) {
    v[i] = p[tid + i * 256];
    ss += v[i] * v[i];
  }
  __shared__ float red[4];
  float wsum = wave_sum(ss);
  if ((tid & 63) == 0) red[tid >> 6] = wsum;
  __syncthreads();
  float tot = red[0] + red[1] + red[2] + red[3];
  float rn = rsqrtf(tot / (float)Dc + 1e-6f);
  float* o = out + (size_t)bt * Dc;
#pragma unroll
  for (int i = 0; i < 4; ++i) o[tid + i * 256] = v[i] * rn;
}

// ---------------------------------------------------------------------------
// Generic GEMM: C[M,N] = epi( A[M,K] @ W[N,K].T )
//   epi: act==1 -> leaky(0.5) then square; then *colscale[n]; then +base[m,n]
// 64x64 tile, BK=16, 256 threads, 4x4 per thread.
// Requires K % 16 == 0, M % 64 == 0. N arbitrary.
// ---------------------------------------------------------------------------
__global__ __launch_bounds__(256) void gemm_kernel(
    const float* __restrict__ A, const float* __restrict__ W,
    float* __restrict__ C, const float* __restrict__ base,
    const float* __restrict__ colscale, int M, int N, int K, int act) {
  __shared__ float As[16][68];  // [k][m], pad 4 -> 16B-aligned rows, no conflicts
  __shared__ float Bs[16][68];  // [k][n]
  int tid = threadIdx.x;
  int tx = tid & 15, ty = tid >> 4;
  int m0 = blockIdx.y * 64, n0 = blockIdx.x * 64;
  int r = tid >> 2, c4 = tid & 3;  // loader: row, float4-col
  float acc[4][4] = {};
  for (int k0 = 0; k0 < K; k0 += 16) {
    // A tile: 64x16 floats = 256 float4, one per thread
    {
      int gm = m0 + r;
      float4 a4 = *(const float4*)(A + (size_t)gm * K + k0 + c4 * 4);
      As[c4 * 4 + 0][r] = a4.x;
      As[c4 * 4 + 1][r] = a4.y;
      As[c4 * 4 + 2][r] = a4.z;
      As[c4 * 4 + 3][r] = a4.w;
    }
    {
      int gn = n0 + r;
      float4 w4;
      if (gn < N)
        w4 = *(const float4*)(W + (size_t)gn * K + k0 + c4 * 4);
      else
        w4 = make_float4(0.f, 0.f, 0.f, 0.f);
      Bs[c4 * 4 + 0][r] = w4.x;
      Bs[c4 * 4 + 1][r] = w4.y;
      Bs[c4 * 4 + 2][r] = w4.z;
      Bs[c4 * 4 + 3][r] = w4.w;
    }
    __syncthreads();
#pragma unroll
    for (int kk = 0; kk < 16; ++kk) {
      float a[4], b[4];
#pragma unroll
      for (int i = 0; i < 4; ++i) a[i] = As[kk][ty * 4 + i];
#pragma unroll
      for (int j = 0; j < 4; ++j) b[j] = Bs[kk][tx * 4 + j];
#pragma unroll
      for (int i = 0; i < 4; ++i)
#pragma unroll
        for (int j = 0; j < 4; ++j) acc[i][j] += a[i] * b[j];
    }
    __syncthreads();
  }
  // epilogue
#pragma unroll
  for (int i = 0; i < 4; ++i) {
    int m = m0 + ty * 4 + i;
#pragma unroll
    for (int j = 0; j < 4; ++j) {
      int n = n0 + tx * 4 + j;
      if (n >= N) continue;
      float v = acc[i][j];
      if (act == 1) {
        float h = (v >= 0.f) ? v : 0.5f * v;
        v = h * h;
      }
      if (colscale) v *= colscale[n];
      if (base) v += base[(size_t)m * N + n];
      C[(size_t)m * N + n] = v;
    }
  }
}

// ---------------------------------------------------------------------------
// QK head-RMS + RoPE (+q_gain). Block per token; wave w handles q heads
// {w, w+4, w+8, w+12} and kv head w. lane = dim within head.
// ---------------------------------------------------------------------------
__global__ __launch_bounds__(256) void qkrope_kernel(
    float* __restrict__ q, float* __restrict__ k,
    const float* __restrict__ q_gain) {
  int bt = blockIdx.x;
  int t = bt % Tc;
  int tid = threadIdx.x;
  int lane = tid & 63, wv = tid >> 6;
  int fi = lane & 31;
  // inv = 10000^(-2*fi/64); angle = t * inv
  float inv = expf(-(float)(2 * fi) * (9.210340372f / 64.f));
  float ang = (float)t * inv;
  float cv = cosf(ang);
  float sv = sinf(ang);

#pragma unroll
  for (int hh = 0; hh < 4; ++hh) {
    int h = wv + hh * 4;
    float* qp = q + (size_t)bt * Dc + h * 64;
    float val = qp[lane];
    float ss = wave_sum(val * val);
    float rn = rsqrtf(ss / 64.f + 1e-6f);
    val *= rn;
    float partner = __shfl(val, lane ^ 32);
    float out = (lane < 32) ? (val * cv + partner * sv) : (val * cv - partner * sv);
    out *= q_gain[h];
    qp[lane] = out;
  }
  {
    int h = wv;  // 4 waves == HKV heads
    float* kp = k + (size_t)bt * KVDc + h * 64;
    float val = kp[lane];
    float ss = wave_sum(val * val);
    float rn = rsqrtf(ss / 64.f + 1e-6f);
    val *= rn;
    float partner = __shfl(val, lane ^ 32);
    float out = (lane < 32) ? (val * cv + partner * sv) : (val * cv - partner * sv);
    kp[lane] = out;
  }
}

// ---------------------------------------------------------------------------
// Causal GQA attention + v-direction-removal epilogue.
// Grid: (T, B*HKV). Block 256 = 4 waves = the G=4 query heads of this kv head.
// Wave-per-query-row flash: lane==key within tile for scores; lane==dim for PV.
// ---------------------------------------------------------------------------
__global__ __launch_bounds__(256) void attn_kernel(
    const float* __restrict__ q, const float* __restrict__ k,
    const float* __restrict__ v, float* __restrict__ y) {
  __shared__ float kt[64][65];
  __shared__ float vt[64][65];
  int qpos = blockIdx.x;
  int bh = blockIdx.y;
  int b = bh / HKVc, hkv = bh % HKVc;
  int tid = threadIdx.x;
  int lane = tid & 63, wv = tid >> 6;
  int h = hkv * 4 + wv;

  float qv = q[((size_t)(b * Tc + qpos)) * Dc + h * 64 + lane];
  float m_run = NEG_BIG, l_run = 0.f, o = 0.f;
  int ntiles = qpos / 64 + 1;
  for (int jt = 0; jt < ntiles; ++jt) {
    // stage 64 keys + 64 values (64x64 each)
#pragma unroll
    for (int i = 0; i < 4; ++i) {
      int idx = tid + i * 256;      // 0..1023 float4 slots
      int rr = idx >> 4;            // row 0..63
      int cc = idx & 15;            // float4 col 0..15
      size_t off = ((size_t)(b * Tc + jt * 64 + rr)) * KVDc + hkv * 64 + cc * 4;
      float4 k4 = *(const float4*)(k + off);
      float4 v4 = *(const float4*)(v + off);
      kt[rr][cc * 4 + 0] = k4.x; kt[rr][cc * 4 + 1] = k4.y;
      kt[rr][cc * 4 + 2] = k4.z; kt[rr][cc * 4 + 3] = k4.w;
      vt[rr][cc * 4 + 0] = v4.x; vt[rr][cc * 4 + 1] = v4.y;
      vt[rr][cc * 4 + 2] = v4.z; vt[rr][cc * 4 + 3] = v4.w;
    }
    __syncthreads();
    // scores: lane = key index in tile
    float s = 0.f;
#pragma unroll 8
    for (int d = 0; d < 64; ++d) {
      float qd = __shfl(qv, d);
      s += kt[lane][d] * qd;
    }
    s *= 0.125f;  // 1/sqrt(64)
    int jg = jt * 64 + lane;
    if (jg > qpos) s = NEG_BIG;
    float mt = wave_max(s);
    float m_new = fmaxf(m_run, mt);
    float alpha = expf(m_run - m_new);
    float p = expf(s - m_new);
    float psum = wave_sum(p);
    l_run = l_run * alpha + psum;
    m_run = m_new;
    o *= alpha;
    // PV: lane = dim
#pragma unroll 8
    for (int j = 0; j < 64; ++j) {
      float pj = __shfl(p, j);
      o += pj * vt[j][lane];
    }
    __syncthreads();
  }
  o /= l_run;
  // remove component along normalized v at query position
  float vv = v[((size_t)(b * Tc + qpos)) * KVDc + hkv * 64 + lane];
  float n2 = wave_sum(vv * vv);
  float nrm = sqrtf(n2);
  float vn = vv / fmaxf(nrm, 1e-12f);
  float dt = wave_sum(o * vn);
  float yo = o - dt * vn;
  y[((size_t)(b * Tc + qpos)) * Dc + h * 64 + lane] = yo;
}

// ---------------------------------------------------------------------------
extern "C" void kernel_launch(void* const* d_in, const int* in_sizes, int n_in,
                              void* d_out, int out_size, void* d_ws,
                              size_t ws_size, hipStream_t stream) {
  const int* ids          = (const int*)d_in[0];
  const float* embed_w    = (const float*)d_in[1];
  const float* big_w      = (const float*)d_in[2];
  const float* big_proj   = (const float*)d_in[3];
  const float* big_scale  = (const float*)d_in[4];
  const float* smear_gate = (const float*)d_in[5];
  const float* ve_w       = (const float*)d_in[6];
  const float* ve_proj    = (const float*)d_in[7];
  const float* ve_scale   = (const float*)d_in[8];
  const float* Wq         = (const float*)d_in[9];
  const float* Wk         = (const float*)d_in[10];
  const float* Wv         = (const float*)d_in[11];
  const float* Wo         = (const float*)d_in[12];
  const float* q_gain     = (const float*)d_in[13];
  const float* attn_scale = (const float*)d_in[14];
  const float* mlp_scale  = (const float*)d_in[15];
  const float* resid_mix  = (const float*)d_in[16];
  const float* Wfc        = (const float*)d_in[17];
  const float* Wp         = (const float*)d_in[18];
  const float* head_w     = (const float*)d_in[19];
  float* out = (float*)d_out;

  float* ws = (float*)d_ws;
  float* x    = ws;
  float* x0   = ws + SZ_X;
  float* x_in = ws + 2 * SZ_X;
  float* xn   = ws + 3 * SZ_X;
  float* qb   = ws + 4 * SZ_X;
  float* yb   = ws + 5 * SZ_X;
  float* kb   = ws + 6 * SZ_X;
  float* vb   = ws + 6 * SZ_X + SZ_KV;
  float* vemb = ws + 6 * SZ_X + 2 * SZ_KV;
  float* hbuf = ws + 6 * SZ_X + 3 * SZ_KV;  // SZ_H floats
  float* raw_x = hbuf;                       // alias: raw_x dead before MLP

  // 1. embedding + bigram + v_embed
  embed_kernel<<<NTOK, 256, 0, stream>>>(ids, embed_w, big_w, big_proj,
                                         big_scale, ve_w, ve_proj, ve_scale,
                                         raw_x, vemb);
  // 2. smear
  smear_kernel<<<(int)(SZ_X / 256), 256, 0, stream>>>(raw_x, smear_gate, x, x0);

  for (int l = 0; l < Lc; ++l) {
    const float* mix = resid_mix + (size_t)l * 2 * Dc;
    prelayer_kernel<<<NTOK, 256, 0, stream>>>(x, x0, mix, x_in, xn);
    // q,k,v projections
    gemm_kernel<<<dim3(Dc / 64, NTOK / 64), 256, 0, stream>>>(
        xn, Wq + (size_t)l * Dc * Dc, qb, nullptr, nullptr, NTOK, Dc, Dc, 0);
    gemm_kernel<<<dim3(KVDc / 64, NTOK / 64), 256, 0, stream>>>(
        xn, Wk + (size_t)l * KVDc * Dc, kb, nullptr, nullptr, NTOK, KVDc, Dc, 0);
    gemm_kernel<<<dim3(KVDc / 64, NTOK / 64), 256, 0, stream>>>(
        xn, Wv + (size_t)l * KVDc * Dc, vb, vemb, nullptr, NTOK, KVDc, Dc, 0);
    // per-head rms + rope + gain
    qkrope_kernel<<<NTOK, 256, 0, stream>>>(qb, kb, q_gain + (size_t)l * Hc);
    // attention
    attn_kernel<<<dim3(Tc, Bc * HKVc), 256, 0, stream>>>(qb, kb, vb, yb);
    // out proj + residual: x = x_in + attn_scale * (y @ Wo.T)
    gemm_kernel<<<dim3(Dc / 64, NTOK / 64), 256, 0, stream>>>(
        yb, Wo + (size_t)l * Dc * Dc, x, x_in, attn_scale + (size_t)l * Dc,
        NTOK, Dc, Dc, 0);
    // MLP
    rms_kernel<<<NTOK, 256, 0, stream>>>(x, xn);
    gemm_kernel<<<dim3(MLPc / 64, NTOK / 64), 256, 0, stream>>>(
        xn, Wfc + (size_t)l * MLPc * Dc, hbuf, nullptr, nullptr, NTOK, MLPc,
        Dc, 1);
    gemm_kernel<<<dim3(Dc / 64, NTOK / 64), 256, 0, stream>>>(
        hbuf, Wp + (size_t)l * Dc * MLPc, x, x, mlp_scale + (size_t)l * Dc,
        NTOK, Dc, MLPc, 0);
  }

  // final rms + head
  rms_kernel<<<NTOK, 256, 0, stream>>>(x, xn);
  gemm_kernel<<<dim3((Vc + 63) / 64, NTOK / 64), 256, 0, stream>>>(
      xn, head_w, out, nullptr, nullptr, NTOK, Vc, Dc, 0);
}